// Round 15
// baseline (33.868 us; speedup 1.0000x reference)
//
#include <hip/hip_runtime.h>
#include <hip/hip_bf16.h>
#include <hip/hip_fp16.h>

#define NB      8
#define NPTS    4096
#define KSEL    16
#define THREADS 768         // 12 waves: B x4 subs, C x4, A x4; 64 queries/block
#define QPB     64
#define NSLOTS  64
#define HALFPTS (NB*NPTS)   // 32768 points per array

typedef _Float16 f16x8 __attribute__((ext_vector_type(8)));
typedef float    f32x16 __attribute__((ext_vector_type(16)));

__device__ __forceinline__ void ce(float& a, float& b) {
  const float lo = fminf(a, b), hi = fmaxf(a, b);
  a = lo; b = hi;
}
__device__ __forceinline__ float min3f(float a, float b, float c) {
  return fminf(fminf(a, b), c);              // fuses to v_min3_f32
}

// two sorted-2 -> sorted-4 (4 ce)
__device__ __forceinline__ void m22(float* o, const float* a, const float* b) {
  o[0]=a[0]; o[1]=a[1]; o[2]=b[1]; o[3]=b[0];
  ce(o[0],o[2]); ce(o[1],o[3]);
  ce(o[0],o[1]); ce(o[2],o[3]);
}
// two sorted-4 -> sorted-8 (12 ce)
__device__ __forceinline__ void m44(float* o, const float* a, const float* b) {
  o[0]=a[0]; o[1]=a[1]; o[2]=a[2]; o[3]=a[3];
  o[4]=b[3]; o[5]=b[2]; o[6]=b[1]; o[7]=b[0];
  ce(o[0],o[4]); ce(o[1],o[5]); ce(o[2],o[6]); ce(o[3],o[7]);
  ce(o[0],o[2]); ce(o[1],o[3]); ce(o[4],o[6]); ce(o[5],o[7]);
  ce(o[0],o[1]); ce(o[2],o[3]); ce(o[4],o[5]); ce(o[6],o[7]);
}
// two sorted-8 -> sorted-16 (32 ce)
__device__ __forceinline__ void m88(float* o, const float* a, const float* b) {
#pragma unroll
  for (int i = 0; i < 8; ++i) { o[i] = a[i]; o[15 - i] = b[i]; }
#pragma unroll
  for (int d = 8; d >= 1; d >>= 1)
#pragma unroll
    for (int i = 0; i < 16; ++i)
      if ((i & d) == 0) ce(o[i], o[i + d]);
}
// keep smallest-16 of two sorted-16 lists, in place in h.
__device__ __forceinline__ void keep16(float* h, const float* g) {
#pragma unroll
  for (int i = 0; i < KSEL; ++i) h[i] = fminf(h[i], g[KSEL - 1 - i]);
#pragma unroll
  for (int d = 8; d >= 1; d >>= 1)
#pragma unroll
    for (int i = 0; i < KSEL; ++i)
      if ((i & d) == 0) ce(h[i], h[i + d]);
}
// h[8] slice-minima -> f[16] sorted, merged across lane halves.
__device__ __forceinline__ void compress8(float* h, float* f) {
  ce(h[0],h[1]); ce(h[2],h[3]); ce(h[4],h[5]); ce(h[6],h[7]);
  float s4a[4], s4b[4], f8[8], g8[8];
  m22(s4a, h + 0, h + 2); m22(s4b, h + 4, h + 6);
  m44(f8, s4a, s4b);
#pragma unroll
  for (int i = 0; i < 8; ++i) g8[i] = __shfl_xor(f8[i], 32);
  m88(f, f8, g8);
}

// Pack candidate fragments only: C-role K-vector
// [(-2x)h,(-2x)l,(-2x)h, (-2y)h,(-2y)l,(-2y)h, (-2z)h,(-2z)l | (-2z)h, cnh,cnl,0..]
// dot(Q,C) = -2 q.c + |c|^2 (~1e-6 abs err). Zeroes acc slots (block 0).
extern "C" __global__ __launch_bounds__(256)
void prep_kernel(const float* __restrict__ gts, const float* __restrict__ preds,
                 _Float16* __restrict__ Cg, _Float16* __restrict__ Cp,
                 double* __restrict__ acc) {
  if (blockIdx.x == 0 && threadIdx.x < 3 * NSLOTS) acc[threadIdx.x] = 0.0;
  const int i = blockIdx.x * 256 + threadIdx.x;     // 0..2*HALFPTS-1
  const bool isg = i < HALFPTS;
  const float* __restrict__ src = isg ? gts : preds;
  const int j = isg ? i : i - HALFPTS;
  const float x = src[3*j], y = src[3*j+1], z = src[3*j+2];
  const float cn = fmaf(x, x, fmaf(y, y, z * z));

  const float mx = -2.f*x, my = -2.f*y, mz = -2.f*z;
  const _Float16 mxh = (_Float16)mx, myh = (_Float16)my, mzh = (_Float16)mz;
  const _Float16 mxl = (_Float16)(mx - (float)mxh);
  const _Float16 myl = (_Float16)(my - (float)myh);
  const _Float16 mzl = (_Float16)(mz - (float)mzh);
  const _Float16 cnh = (_Float16)cn;
  const _Float16 cnl = (_Float16)(cn - (float)cnh);
  const _Float16 zr = (_Float16)0.0f;

  _Float16* C = (isg ? Cg : Cp) + (size_t)j * 16;
  C[0]=mxh; C[1]=mxl; C[2]=mxh; C[3]=myh; C[4]=myl; C[5]=myh;
  C[6]=mzh; C[7]=mzl; C[8]=mzh; C[9]=cnh; C[10]=cnl;
  C[11]=zr; C[12]=zr; C[13]=zr; C[14]=zr; C[15]=zr;
}

// Q-role fragment for this lane's half: [xh,xh,xl, yh,yh,yl, zh,zh | zl,1,1,0..]
__device__ __forceinline__ f16x8 make_qfrag(float x, float y, float z, int half) {
  const _Float16 xh = (_Float16)x, yh = (_Float16)y, zh = (_Float16)z;
  f16x8 q;
  if (half == 0) {
    const _Float16 xl = (_Float16)(x - (float)xh);
    const _Float16 yl = (_Float16)(y - (float)yh);
    q[0]=xh; q[1]=xh; q[2]=xl; q[3]=yh; q[4]=yh; q[5]=yl; q[6]=zh; q[7]=zh;
  } else {
    const _Float16 zl = (_Float16)(z - (float)zh);
    const _Float16 one = (_Float16)1.0f, zr = (_Float16)0.0f;
    q[0]=zl; q[1]=one; q[2]=one; q[3]=zr; q[4]=zr; q[5]=zr; q[6]=zr; q[7]=zr;
  }
  return q;
}

// Block: 12 waves, 64 queries (2 strips of 32 cols). role = w>>2 (0=B: gt-cand x
// gt-q topk; 1=C: gt-cand x pred-q min; 2=A: pred-cand x gt-q topk); sub = w&3
// covers cands [sub*1024, +1024) = 32 tiles. Each wave serves BOTH strips per
// tile load (2 MFMAs). Selection: h[8] row-pair min3 -> 64 slices/query.
extern "C" __global__ __launch_bounds__(THREADS, 6)
void fused_kernel(const float* __restrict__ gts, const float* __restrict__ preds,
                  const _Float16* __restrict__ Cg, const _Float16* __restrict__ Cp,
                  double* __restrict__ acc) {
  __shared__ float TQB[2][2][32][KSEL + 1];   // [slot][strip][col][pad17]
  __shared__ float TQA[2][2][32][KSEL + 1];
  __shared__ float TCm[4][2][32];

  const int t    = threadIdx.x;
  const int lane = t & 63;
  const int w    = t >> 6;          // 0..11
  const int col  = lane & 31;
  const int half = lane >> 5;
  const int b    = blockIdx.y;
  const int sp   = blockIdx.x;      // strip-pair 0..63
  const int role = w >> 2;          // 0=B, 1=C, 2=A
  const int sub  = w & 3;

  const size_t qidx0 = (size_t)(b * NPTS) + sp * QPB + col;        // strip 0
  const size_t qidx1 = qidx0 + 32;                                 // strip 1

  const _Float16* __restrict__ cb =
      ((role == 2) ? Cp : Cg) + ((size_t)(b * NPTS + sub * 1024)) * 16;
  const _Float16* __restrict__ p = cb + (size_t)col * 16 + half * 8;

  f32x16 zz;
#pragma unroll
  for (int i = 0; i < 16; ++i) zz[i] = 0.f;

  float f0[KSEL], f1v[KSEL];        // per-strip sorted-16 (topk roles)

  if (role != 1) {
    const float ax0 = gts[3*qidx0], ay0 = gts[3*qidx0+1], az0 = gts[3*qidx0+2];
    const float ax1 = gts[3*qidx1], ay1 = gts[3*qidx1+1], az1 = gts[3*qidx1+2];
    const f16x8 q0 = make_qfrag(ax0, ay0, az0, half);
    const f16x8 q1 = make_qfrag(ax1, ay1, az1, half);
    float h0[8], h1[8];
#pragma unroll
    for (int i = 0; i < 8; ++i) { h0[i] = 1e30f; h1[i] = 1e30f; }
#pragma unroll 2
    for (int tile = 0; tile < 32; ++tile) {
      const f16x8 at = *(const f16x8*)(p + (size_t)tile * 512);
      const f32x16 a0 = __builtin_amdgcn_mfma_f32_32x32x16_f16(at, q0, zz, 0, 0, 0);
#pragma unroll
      for (int j = 0; j < 8; ++j) h0[j] = min3f(h0[j], a0[2*j], a0[2*j + 1]);
      const f32x16 a1 = __builtin_amdgcn_mfma_f32_32x32x16_f16(at, q1, zz, 0, 0, 0);
#pragma unroll
      for (int j = 0; j < 8; ++j) h1[j] = min3f(h1[j], a1[2*j], a1[2*j + 1]);
    }
    compress8(h0, f0);
    compress8(h1, f1v);
    if (sub >= 2 && half == 0) {    // level-1 export (subs 2,3)
      float (*T)[2][32][KSEL+1] = (role == 0) ? TQB : TQA;
#pragma unroll
      for (int i = 0; i < KSEL; ++i) {
        T[sub-2][0][col][i] = f0[i];
        T[sub-2][1][col][i] = f1v[i];
      }
    }
  } else {
    const float px0 = preds[3*qidx0], py0 = preds[3*qidx0+1], pz0 = preds[3*qidx0+2];
    const float px1 = preds[3*qidx1], py1 = preds[3*qidx1+1], pz1 = preds[3*qidx1+2];
    const f16x8 q0 = make_qfrag(px0, py0, pz0, half);
    const f16x8 q1 = make_qfrag(px1, py1, pz1, half);
    float bw0 = 1e30f, bw1 = 1e30f;
#pragma unroll 2
    for (int tile = 0; tile < 32; ++tile) {
      const f16x8 at = *(const f16x8*)(p + (size_t)tile * 512);
      const f32x16 a0 = __builtin_amdgcn_mfma_f32_32x32x16_f16(at, q0, zz, 0, 0, 0);
      bw0 = min3f(bw0,
                  min3f(min3f(a0[0],a0[1],a0[2]),  min3f(a0[3],a0[4],a0[5]),  a0[15]),
                  min3f(min3f(a0[6],a0[7],a0[8]),  min3f(a0[9],a0[10],a0[11]),
                        min3f(a0[12],a0[13],a0[14])));
      const f32x16 a1 = __builtin_amdgcn_mfma_f32_32x32x16_f16(at, q1, zz, 0, 0, 0);
      bw1 = min3f(bw1,
                  min3f(min3f(a1[0],a1[1],a1[2]),  min3f(a1[3],a1[4],a1[5]),  a1[15]),
                  min3f(min3f(a1[6],a1[7],a1[8]),  min3f(a1[9],a1[10],a1[11]),
                        min3f(a1[12],a1[13],a1[14])));
    }
    bw0 = fminf(bw0, __shfl_xor(bw0, 32));
    bw1 = fminf(bw1, __shfl_xor(bw1, 32));
    if (half == 0) { TCm[sub][0][col] = bw0; TCm[sub][1][col] = bw1; }
  }
  __syncthreads();

  // level-1 merge: subs 0,1 absorb subs 2,3. C: sub0 wave reduces all 4.
  if (role != 1 && sub < 2) {
    float (*T)[2][32][KSEL+1] = (role == 0) ? TQB : TQA;
    float g[KSEL];
#pragma unroll
    for (int i = 0; i < KSEL; ++i) g[i] = T[sub][0][col][i];
    keep16(f0, g);
#pragma unroll
    for (int i = 0; i < KSEL; ++i) g[i] = T[sub][1][col][i];
    keep16(f1v, g);
  }
  if (w == 4) {  // C sub0: 4-way min per strip
    const float m0 = fminf(fminf(TCm[0][0][col], TCm[1][0][col]),
                           fminf(TCm[2][0][col], TCm[3][0][col]));
    const float m1 = fminf(fminf(TCm[0][1][col], TCm[1][1][col]),
                           fminf(TCm[2][1][col], TCm[3][1][col]));
    if (half == 0) { TCm[0][0][col] = m0; TCm[0][1][col] = m1; }
  }
  __syncthreads();

  // level-2 export: sub1 -> slot 0
  if (role != 1 && sub == 1 && half == 0) {
    float (*T)[2][32][KSEL+1] = (role == 0) ? TQB : TQA;
#pragma unroll
    for (int i = 0; i < KSEL; ++i) {
      T[0][0][col][i] = f0[i];
      T[0][1][col][i] = f1v[i];
    }
  }
  __syncthreads();

  // finals: w0 (B) merges; w8 (A) merges and exports to TQA[1]
  if (w == 0 || w == 8) {
    float (*T)[2][32][KSEL+1] = (w == 0) ? TQB : TQA;
    float g[KSEL];
#pragma unroll
    for (int i = 0; i < KSEL; ++i) g[i] = T[0][0][col][i];
    keep16(f0, g);
#pragma unroll
    for (int i = 0; i < KSEL; ++i) g[i] = T[0][1][col][i];
    keep16(f1v, g);
    if (w == 8 && half == 0) {
#pragma unroll
      for (int i = 0; i < KSEL; ++i) {
        TQA[1][0][col][i] = f0[i];
        TQA[1][1][col][i] = f1v[i];
      }
    }
  }
  __syncthreads();

  // epilogue in w0: per-half strip assignment, one butterfly covers both strips
  if (w == 0) {
    float fa0[KSEL], fa1[KSEL];
#pragma unroll
    for (int i = 0; i < KSEL; ++i) {
      fa0[i] = TQA[1][0][col][i];
      fa1[i] = TQA[1][1][col][i];
    }
    const float gx0 = gts[3*qidx0], gy0 = gts[3*qidx0+1], gz0 = gts[3*qidx0+2];
    const float gx1 = gts[3*qidx1], gy1 = gts[3*qidx1+1], gz1 = gts[3*qidx1+2];
    const float px0 = preds[3*qidx0], py0 = preds[3*qidx0+1], pz0 = preds[3*qidx0+2];
    const float px1 = preds[3*qidx1], py1 = preds[3*qidx1+1], pz1 = preds[3*qidx1+2];
    const float qn0 = fmaf(gx0,gx0,fmaf(gy0,gy0,gz0*gz0));
    const float qn1 = fmaf(gx1,gx1,fmaf(gy1,gy1,gz1*gz1));
    const float pn0 = fmaf(px0,px0,fmaf(py0,py0,pz0*pz0));
    const float pn1 = fmaf(px1,px1,fmaf(py1,py1,pz1*pz1));

    const float w1_0 = TCm[0][0][col] + pn0, w1_1 = TCm[0][1][col] + pn1;
    const float w2_0 = fa0[0] + qn0,         w2_1 = fa1[0] + qn1;
    float w3_0 = 0.f, w3_1 = 0.f;
#pragma unroll
    for (int i = 0; i < KSEL; ++i) {
      const float d0 = fa0[i] - f0[i];  w3_0 = fmaf(d0, d0, w3_0);
      const float d1 = fa1[i] - f1v[i]; w3_1 = fmaf(d1, d1, w3_1);
    }
    float v1 = half ? w1_1 : w1_0;
    float v2 = half ? w2_1 : w2_0;
    float v3 = half ? w3_1 : w3_0;
#pragma unroll
    for (int off = 32; off >= 1; off >>= 1) {
      v1 += __shfl_xor(v1, off);
      v2 += __shfl_xor(v2, off);
      v3 += __shfl_xor(v3, off);
    }
    if (lane == 0) {
      const int slot = (sp + 13 * b) & (NSLOTS - 1);
      atomicAdd(&acc[0 * NSLOTS + slot], (double)v1);
      atomicAdd(&acc[1 * NSLOTS + slot], (double)v2);
      atomicAdd(&acc[2 * NSLOTS + slot], (double)v3);
    }
  }
}

extern "C" __global__ void finalize_kernel(const double* __restrict__ acc,
                                           float* __restrict__ out) {
  const int l = threadIdx.x;  // 64 threads
  double a = acc[l], b = acc[NSLOTS + l], c = acc[2 * NSLOTS + l];
#pragma unroll
  for (int off = 32; off >= 1; off >>= 1) {
    a += __shfl_xor(a, off);
    b += __shfl_xor(b, off);
    c += __shfl_xor(c, off);
  }
  if (l == 0) {
    const double loss1 = a / (double)((size_t)NB * NPTS);
    const double loss2 = b / (double)((size_t)NB * NPTS);
    const double dens  = c / (double)((size_t)NB * NPTS * KSEL);
    out[0] = (float)(loss1 + loss2);
    out[1] = (float)dens;
  }
}

extern "C" void kernel_launch(void* const* d_in, const int* in_sizes, int n_in,
                              void* d_out, int out_size, void* d_ws, size_t ws_size,
                              hipStream_t stream) {
  const float* gts   = (const float*)d_in[0];
  const float* preds = (const float*)d_in[1];
  char* ws = (char*)d_ws;
  const size_t ARR = (size_t)HALFPTS * 16 * sizeof(_Float16);   // 1 MiB each
  _Float16* Cg = (_Float16*)(ws + 0 * ARR);
  _Float16* Cp = (_Float16*)(ws + 1 * ARR);
  double*  acc = (double*)(ws + 2 * ARR);
  float*   out = (float*)d_out;

  hipLaunchKernelGGL(prep_kernel, dim3(2 * HALFPTS / 256), dim3(256), 0, stream,
                     gts, preds, Cg, Cp, acc);
  hipLaunchKernelGGL(fused_kernel, dim3(NPTS / QPB, NB), dim3(THREADS), 0, stream,
                     gts, preds, Cg, Cp, acc);
  hipLaunchKernelGGL(finalize_kernel, dim3(1), dim3(64), 0, stream, acc, out);
}